// Round 6
// baseline (209.448 us; speedup 1.0000x reference)
//
#include <hip/hip_runtime.h>
#include <hip/hip_bf16.h>
#include <stdint.h>
#include <math.h>

#define SEQ 2048
#define DM 1024
#define NH 16
#define DK 64

typedef __attribute__((ext_vector_type(8))) short short8;
typedef __attribute__((ext_vector_type(4))) short short4v;
typedef __attribute__((ext_vector_type(4))) float f32x4;
typedef __attribute__((ext_vector_type(16))) float f32x16;

__device__ __forceinline__ float bf2f(unsigned short s) {
  unsigned u = ((unsigned)s) << 16; float f; __builtin_memcpy(&f, &u, 4); return f;
}
__device__ __forceinline__ unsigned short f2bf(float f) {
  unsigned u; __builtin_memcpy(&u, &f, 4);
  u += 0x7FFFu + ((u >> 16) & 1u);          // RNE
  return (unsigned short)(u >> 16);
}
__device__ __forceinline__ unsigned cvt_pk_bf16(float lo, float hi) {
  unsigned r;
  asm("v_cvt_pk_bf16_f32 %0, %1, %2" : "=v"(r) : "v"(lo), "v"(hi));
  return r;   // [bf16(hi)<<16 | bf16(lo)]
}
__device__ __forceinline__ f32x4 mfma16(short8 a, short8 b, f32x4 c) {
  return __builtin_amdgcn_mfma_f32_16x16x32_bf16(a, b, c, 0, 0, 0);
}
__device__ __forceinline__ f32x16 mfma32(short8 a, short8 b, f32x16 c) {
  return __builtin_amdgcn_mfma_f32_32x32x16_bf16(a, b, c, 0, 0, 0);
}
__device__ __forceinline__ void gload_lds16(const void* g, void* l) {
  __builtin_amdgcn_global_load_lds((const __attribute__((address_space(1))) void*)g,
                                   (__attribute__((address_space(3))) void*)l, 16, 0, 0);
}

// ---------------- prep: fp32 -> bf16 for x and the 4 weight matrices ----------------
__global__ __launch_bounds__(256) void prep_kernel(
    const float* __restrict__ x, const float* __restrict__ Wq,
    const float* __restrict__ Wk, const float* __restrict__ Wv,
    const float* __restrict__ Wo, __hip_bfloat16* __restrict__ xb,
    __hip_bfloat16* __restrict__ Wb) {
  int chunk = blockIdx.x * 256 + threadIdx.x;   // 1,048,576 chunks of 8 elems
  const float* src; __hip_bfloat16* dst;
  if (chunk < 524288) { src = x + (size_t)chunk * 8; dst = xb + (size_t)chunk * 8; }
  else {
    int wc = chunk - 524288; int wi = wc >> 17; int wo_ = wc & 131071;
    const float* Ws = (wi == 0) ? Wq : (wi == 1) ? Wk : (wi == 2) ? Wv : Wo;
    src = Ws + (size_t)wo_ * 8; dst = Wb + (size_t)wi * 1048576 + (size_t)wo_ * 8;
  }
  float4 a = *(const float4*)src; float4 b = *(const float4*)(src + 4);
  union { short8 v; unsigned short e[8]; } u;
  u.e[0] = f2bf(a.x); u.e[1] = f2bf(a.y); u.e[2] = f2bf(a.z); u.e[3] = f2bf(a.w);
  u.e[4] = f2bf(b.x); u.e[5] = f2bf(b.y); u.e[6] = f2bf(b.z); u.e[7] = f2bf(b.w);
  *(short8*)dst = u.v;
}

// ---------------- RoPE cos/sin table: [2048][32] float2 ----------------
__global__ __launch_bounds__(256) void rope_table_kernel(float2* __restrict__ tab) {
  int idx = blockIdx.x * 256 + threadIdx.x;   // 65536
  int s = idx >> 5, i = idx & 31;
  float fr = powf(10000.0f, -(float)i * (1.0f / 32.0f));
  float ang = (float)s * fr;
  tab[idx] = make_float2(cosf(ang), sinf(ang));
}

// ============ 256^2 8-phase GEMM (m201 template): C[M][N] = A @ W^T, bf16 ============
__global__ __launch_bounds__(512, 1) void gemm256(
    const __hip_bfloat16* __restrict__ A, const __hip_bfloat16* __restrict__ W,
    __hip_bfloat16* __restrict__ C, const int N) {
  extern __shared__ char lds[];
  char* ldsA = lds;              // 64KB: db(2) x half(2) x 16KB
  char* ldsB = lds + 65536;      // 64KB
  const int t = threadIdx.x;
  int wg = blockIdx.x;
  const int cpx = gridDim.x >> 3;                 // grid % 8 == 0
  wg = (wg & 7) * cpx + (wg >> 3);                // bijective XCD swizzle
  const int ntl = N >> 8;
  const int mt = wg / ntl, nt = wg % ntl;
  const int m0 = mt << 8, n0 = nt << 8;
  const int w = t >> 6, lane = t & 63, l15 = lane & 15, hi = lane >> 4;
  const int wm = w >> 2, wn = w & 3;
  const int lr = t >> 3;
  const int csw = ((t & 7) ^ (lr & 7)) * 8;       // inverse-swizzled source elem offset
  const __hip_bfloat16* aS = A + (size_t)(m0 + lr) * 1024 + csw;
  const __hip_bfloat16* bS = W + (size_t)(n0 + lr) * 1024 + csw;
  char* ldA1 = ldsA + t * 16; char* ldA2 = ldsA + (t + 512) * 16;
  char* ldB1 = ldsB + t * 16; char* ldB2 = ldsB + (t + 512) * 16;
#define STG_A(kt, db, mh) { \
    const __hip_bfloat16* s_ = aS + (size_t)(mh) * 131072 + (kt) * 64; \
    gload_lds16(s_,              ldA1 + (db) * 32768 + (mh) * 16384);  \
    gload_lds16(s_ + 65536,      ldA2 + (db) * 32768 + (mh) * 16384); }
#define STG_B(kt, db, nh) { \
    const __hip_bfloat16* s_ = bS + (size_t)(nh) * 131072 + (kt) * 64; \
    gload_lds16(s_,              ldB1 + (db) * 32768 + (nh) * 16384);  \
    gload_lds16(s_ + 65536,      ldB2 + (db) * 32768 + (nh) * 16384); }
  int lrA[4], lrB[2];
#pragma unroll
  for (int mi = 0; mi < 4; ++mi) lrA[mi] = wm * 64 + mi * 16 + l15;
#pragma unroll
  for (int ni = 0; ni < 2; ++ni) lrB[ni] = wn * 32 + ni * 16 + l15;
  f32x4 acc[8][4] = {};
  short8 afr[4][2], bfr[2][2][2];
  auto rdA = [&](int db, int mh) {
#pragma unroll
    for (int mi = 0; mi < 4; ++mi)
#pragma unroll
      for (int ks = 0; ks < 2; ++ks) {
        int off = db * 32768 + mh * 16384 + lrA[mi] * 128 +
                  ((((ks << 2) + hi) ^ (lrA[mi] & 7)) << 4);
        afr[mi][ks] = *(const short8*)(ldsA + off);
      }
  };
  auto rdB = [&](int db, int nh) {
#pragma unroll
    for (int ni = 0; ni < 2; ++ni)
#pragma unroll
      for (int ks = 0; ks < 2; ++ks) {
        int off = db * 32768 + nh * 16384 + lrB[ni] * 128 +
                  ((((ks << 2) + hi) ^ (lrB[ni] & 7)) << 4);
        bfr[nh][ni][ks] = *(const short8*)(ldsB + off);
      }
  };
  auto quad = [&](int mh, int nh) {
    __builtin_amdgcn_s_setprio(1);
#pragma unroll
    for (int mi = 0; mi < 4; ++mi)
#pragma unroll
      for (int ni = 0; ni < 2; ++ni)
#pragma unroll
        for (int ks = 0; ks < 2; ++ks)
          acc[mh * 4 + mi][nh * 2 + ni] =
              mfma16(afr[mi][ks], bfr[nh][ni][ks], acc[mh * 4 + mi][nh * 2 + ni]);
    __builtin_amdgcn_s_setprio(0);
  };
  // prologue: stage kt=0 (db=0), order [Alo, Blo, Bhi, Ahi]
  STG_A(0, 0, 0); STG_B(0, 0, 0); STG_B(0, 0, 1); STG_A(0, 0, 1);
  asm volatile("s_waitcnt vmcnt(4)" ::: "memory");   // Alo,Blo landed
  __builtin_amdgcn_s_barrier();
  for (int kt = 0; kt < 16; ++kt) {
    const int db = kt & 1, dn = db ^ 1;
    const bool nl = (kt < 15);
    // p0: quadrant (0,0)
    rdA(db, 0); rdB(db, 0);
    if (nl) { STG_A(kt + 1, dn, 0);
      asm volatile("s_waitcnt vmcnt(4)" ::: "memory"); }
    else     asm volatile("s_waitcnt vmcnt(2)" ::: "memory");
    __builtin_amdgcn_s_barrier();
    quad(0, 0);
    __builtin_amdgcn_s_barrier();
    // p1: quadrant (0,1)
    rdB(db, 1);
    if (nl) { STG_B(kt + 1, dn, 0);
      asm volatile("s_waitcnt vmcnt(4)" ::: "memory"); }
    else     asm volatile("s_waitcnt vmcnt(0)" ::: "memory");
    __builtin_amdgcn_s_barrier();
    quad(0, 1);
    __builtin_amdgcn_s_barrier();
    // p2: quadrant (1,0) — nothing must land here (vmcnt(6) trace-verified)
    rdA(db, 1);
    if (nl) { STG_B(kt + 1, dn, 1);
      asm volatile("s_waitcnt vmcnt(6)" ::: "memory"); }
    __builtin_amdgcn_s_barrier();
    quad(1, 0);
    __builtin_amdgcn_s_barrier();
    // p3: quadrant (1,1)
    if (nl) { STG_A(kt + 1, dn, 1);
      asm volatile("s_waitcnt vmcnt(4)" ::: "memory"); }
    __builtin_amdgcn_s_barrier();
    quad(1, 1);
    __builtin_amdgcn_s_barrier();
  }
#undef STG_A
#undef STG_B
  unsigned short* Cb = (unsigned short*)C;
#pragma unroll
  for (int MI = 0; MI < 8; ++MI) {
    const int m = m0 + (MI >> 2) * 128 + wm * 64 + (MI & 3) * 16 + hi * 4;
#pragma unroll
    for (int NI = 0; NI < 4; ++NI) {
      const int n = n0 + (NI >> 1) * 128 + wn * 32 + (NI & 1) * 16 + l15;
#pragma unroll
      for (int r = 0; r < 4; ++r)
        Cb[(size_t)(m + r) * N + n] = f2bf(acc[MI][NI][r]);
    }
  }
}

// ---------------- GEMM 128xBN (out-proj): C fp32 = A[M][1024] @ W[N][1024]^T ----
template<int BN>
__global__ __launch_bounds__(256) void gemm_bt(
    const __hip_bfloat16* __restrict__ A, const __hip_bfloat16* __restrict__ W,
    float* __restrict__ C, const int N) {
  constexpr int NI = BN / 32;
  constexpr int WN = BN / 2;
  __shared__ alignas(16) __hip_bfloat16 As[128 * 32];
  __shared__ alignas(16) __hip_bfloat16 Bs[BN * 32];
  const int t = threadIdx.x;
  const int m0 = blockIdx.x * 128, n0 = blockIdx.y * BN;
  const int w = t >> 6, lane = t & 63, l15 = lane & 15, hi = lane >> 4;
  const int wm = w >> 1, wn = w & 1;
  const int srow = t >> 2, scs = (t & 3) ^ (srow & 3);
  const __hip_bfloat16* aSrcA = A + (size_t)(m0 + srow) * DM + scs * 8;
  const __hip_bfloat16* aSrcB = aSrcA + (size_t)64 * DM;
  const __hip_bfloat16* bSrcA = W + (size_t)(n0 + srow) * DM + scs * 8;
  const __hip_bfloat16* bSrcB = bSrcA + (size_t)64 * DM;
  char* aDstA = (char*)As + t * 16; char* aDstB = (char*)As + (t + 256) * 16;
  char* bDstA = (char*)Bs + t * 16; char* bDstB = (char*)Bs + (t + 256) * 16;
  const int r3 = l15 & 3;
  int aoff[4], boff[NI];
#pragma unroll
  for (int i = 0; i < 4; ++i)
    aoff[i] = (wm * 64 + i * 16 + l15) * 64 + ((hi ^ r3) * 16);
#pragma unroll
  for (int i = 0; i < NI; ++i)
    boff[i] = (wn * WN + i * 16 + l15) * 64 + ((hi ^ r3) * 16);
  f32x4 acc[4][NI] = {};
  for (int kt = 0; kt < DM; kt += 32) {
    gload_lds16(aSrcA + kt, aDstA);
    gload_lds16(aSrcB + kt, aDstB);
    gload_lds16(bSrcA + kt, bDstA);
    if (BN == 128) gload_lds16(bSrcB + kt, bDstB);
    __syncthreads();
    short8 af[4], bfv[NI];
#pragma unroll
    for (int i = 0; i < 4; ++i) af[i] = *(const short8*)((const char*)As + aoff[i]);
#pragma unroll
    for (int i = 0; i < NI; ++i) bfv[i] = *(const short8*)((const char*)Bs + boff[i]);
#pragma unroll
    for (int mi = 0; mi < 4; ++mi)
#pragma unroll
      for (int ni = 0; ni < NI; ++ni)
        acc[mi][ni] = mfma16(af[mi], bfv[ni], acc[mi][ni]);
    __syncthreads();
  }
  const int mBase = m0 + wm * 64, nBase = n0 + wn * WN;
#pragma unroll
  for (int mi = 0; mi < 4; ++mi)
#pragma unroll
    for (int ni = 0; ni < NI; ++ni) {
      int m = mBase + mi * 16 + hi * 4, n = nBase + ni * 16 + l15;
#pragma unroll
      for (int r = 0; r < 4; ++r)
        C[(size_t)(m + r) * N + n] = acc[mi][ni][r];
    }
}

// ---------------- RoPE: rotate Q (cols 0..1023) and K (cols 1024..2047) in place ----
__global__ __launch_bounds__(256) void rope_kernel(
    __hip_bfloat16* __restrict__ QKV, const float2* __restrict__ tab) {
  int chunk = blockIdx.x * 256 + threadIdx.x;   // 4096 rows * 256 chunks
  int row = chunk >> 8; int c0 = (chunk & 255) << 3;
  int s = row & (SEQ - 1);
  const float2* tb = tab + s * 32 + ((c0 & 63) >> 1);
  __hip_bfloat16* p = QKV + (size_t)row * 3072 + c0;
  union { short8 v; unsigned short e[8]; } u; u.v = *(const short8*)p;
  union { short8 v; unsigned short e[8]; } o;
#pragma unroll
  for (int k = 0; k < 4; ++k) {
    float2 cs = tb[k];
    float x1 = bf2f(u.e[2 * k]), x2 = bf2f(u.e[2 * k + 1]);
    o.e[2 * k]     = f2bf(cs.x * x1 - cs.y * x2);
    o.e[2 * k + 1] = f2bf(cs.y * x1 + cs.x * x2);
  }
  *(short8*)p = o.v;
}

// ---------------- V transpose: Vt[bh][d][s] = V[b][s][h*64+d] ----------------
__global__ __launch_bounds__(256) void transpose_v(
    const __hip_bfloat16* __restrict__ QKV, __hip_bfloat16* __restrict__ Vt) {
  const int st = blockIdx.x, bh = blockIdx.y, b = bh >> 4, h = bh & 15;
  __shared__ alignas(16) __hip_bfloat16 tile[64][80];   // pad 16 -> 160B rows
  const int t = threadIdx.x, s0 = st * 64;
#pragma unroll
  for (int i = 0; i < 2; ++i) {
    int idx = i * 256 + t; int r = idx >> 3, c = idx & 7;
    short8 v = *(const short8*)(QKV + (size_t)(b * SEQ + s0 + r) * 3072 + 2048 + h * 64 + c * 8);
    *(short8*)&tile[r][c * 8] = v;
  }
  __syncthreads();
#pragma unroll
  for (int i = 0; i < 2; ++i) {
    int idx = i * 256 + t; int d = idx >> 3, c = idx & 7;
    union { short8 v; short e[8]; } u;
#pragma unroll
    for (int j = 0; j < 8; ++j) u.e[j] = *(short*)&tile[c * 8 + j][d];
    *(short8*)(Vt + ((size_t)bh * 64 + d) * SEQ + s0 + c * 8) = u.v;
  }
}

// ======== Flash attention R6: 32x32 MFMA, swapped QK^T, LANE-LOCAL softmax ========
// 4 waves x 32 q-rows (QBLK=128); KV tiles 64; grid 512 = 32bh x 16qb, XCD-pinned bh,
// heavy-first. S^T=mfma32(K,Q): lane l holds 16 P-vals (4-interleaved kv) of q=l&31;
// lanes l,l+32 complementary -> softmax = in-reg tree + one shfl_xor(32).
// P^T->B-op: 16 cvt_pk + 8 permlane32_swap per tile (T12). No ds_bpermute.
__global__ __launch_bounds__(256) void attn_kernel(
    const __hip_bfloat16* __restrict__ QKV, const __hip_bfloat16* __restrict__ Vt,
    __hip_bfloat16* __restrict__ Ao) {
  const int id = blockIdx.x;
  const int bh = (id & 7) * 4 + ((id >> 3) & 3);   // id%8 constant per bh -> same XCD
  const int qb = 15 - (id >> 5);                   // heavy blocks dispatch first
  const int b = bh >> 4, h = bh & 15;
  __shared__ alignas(16) __hip_bfloat16 Ks[2][64 * 64];
  __shared__ alignas(16) __hip_bfloat16 Vs[2][64 * 64];
  const int t = threadIdx.x, w = t >> 6, lane = t & 63;
  const int l31 = lane & 31, h32 = lane >> 5;
  const int q0w = qb * 128 + w * 32;               // wave's first q row
  const int qg = q0w + l31;                        // this lane's q row
  const int kvt_d = q0w >> 6;                      // wave's diagonal tile
  const int nt = 2 * qb + 2;                       // KV tiles for this block
  constexpr float SC = 0.18033688f;                // 0.125 * log2(e)
  constexpr float THR = 11.541560f;                // 8 nats in log2
  // Q fragments (B-operand): lane: col q=l31, k = kk*16 + h32*8 + 0..7
  const __hip_bfloat16* Qp = QKV + (size_t)(b * SEQ + qg) * 3072 + h * 64 + h32 * 8;
  short8 qf[4];
#pragma unroll
  for (int kk = 0; kk < 4; ++kk) qf[kk] = *(const short8*)(Qp + kk * 16);
  // staging (R5 skeleton): 256 threads x (2 K + 2 V) 16B chunks per 64-row tile
  const int sr = t >> 3, sc = t & 7, scs = sc ^ (sr & 7);
  const __hip_bfloat16* kSrcA = QKV + (size_t)(b * SEQ + sr) * 3072 + DM + h * 64 + scs * 8;
  const __hip_bfloat16* kSrcB = kSrcA + (size_t)32 * 3072;
  const __hip_bfloat16* vSrcA = Vt + ((size_t)bh * 64 + sr) * SEQ + scs * 8;
  const __hip_bfloat16* vSrcB = vSrcA + (size_t)32 * SEQ;
  char* kDstA = (char*)Ks + t * 16;  char* kDstB = (char*)Ks + (t + 256) * 16;
  char* vDstA = (char*)Vs + t * 16;  char* vDstB = (char*)Vs + (t + 256) * 16;
  f32x16 ot0 = {}, ot1 = {};                       // O^T acc: d 0..31 / 32..63
  float m_run = -INFINITY, l_run = 0.0f;

  // stage tile 0 -> buf 0
  gload_lds16(kSrcA, kDstA);
  gload_lds16(kSrcB, kDstB);
  gload_lds16(vSrcA, vDstA);
  gload_lds16(vSrcB, vDstB);

  for (int kvt = 0; kvt < nt; ++kvt) {
    const int cur = kvt & 1;
    if (kvt + 1 < nt) {
      const size_t ko = (size_t)((kvt + 1) * 64) * 3072;
      const int vo = (kvt + 1) * 64;
      gload_lds16(kSrcA + ko, kDstA + (cur ^ 1) * 8192);
      gload_lds16(kSrcB + ko, kDstB + (cur ^ 1) * 8192);
      gload_lds16(vSrcA + vo, vDstA + (cur ^ 1) * 8192);
      gload_lds16(vSrcB + vo, vDstB + (cur ^ 1) * 8192);
      __builtin_amdgcn_sched_barrier(0);
      asm volatile("s_waitcnt vmcnt(4)" ::: "memory");
    } else {
      __builtin_amdgcn_sched_barrier(0);
      asm volatile("s_waitcnt vmcnt(0)" ::: "memory");
    }
    __builtin_amdgcn_s_barrier();
    __builtin_amdgcn_sched_barrier(0);

    if (kvt <= kvt_d) {                            // wave-uniform
      const char* Kbase = (const char*)Ks + cur * 8192;
      const char* Vbase = (const char*)Vs + cur * 8192;
      const int cxor = l31 & 7;
      // ---- QK^T: S^T[kv][q], two 32-kv halves ----
      f32x16 st0 = {}, st1 = {};
      __builtin_amdgcn_s_setprio(1);
#pragma unroll
      for (int kk = 0; kk < 4; ++kk) {
        const int c = ((2 * kk + h32) ^ cxor) * 16;
        short8 k0 = *(const short8*)(Kbase + l31 * 128 + c);
        short8 k1 = *(const short8*)(Kbase + (32 + l31) * 128 + c);
        st0 = mfma32(k0, qf[kk], st0);
        st1 = mfma32(k1, qf[kk], st1);
      }
      __builtin_amdgcn_s_setprio(0);
      // ---- causal mask (diag tile only) ----
      if (kvt == kvt_d) {
        const int base = qg - kvt * 64;
#pragma unroll
        for (int r = 0; r < 16; ++r) {
          const int co = (r & 3) + 8 * (r >> 2) + 4 * h32;
          st0[r] = (co <= base) ? st0[r] : -INFINITY;
          st1[r] = (co + 32 <= base) ? st1[r] : -INFINITY;
        }
      }
      // ---- lane-local max (tree) + cross-half combine ----
      float tm[16];
#pragma unroll
      for (int r = 0; r < 16; ++r) tm[r] = fmaxf(st0[r], st1[r]);
#pragma unroll
      for (int s = 8; s > 0; s >>= 1)
#pragma unroll
        for (int r = 0; r < s; ++r) tm[r] = fmaxf(tm[r], tm[r + s]);
      float mt = fmaxf(tm[0], __shfl_xor(tm[0], 32, 64)) * SC;
      if (!__all(mt <= m_run + THR)) {             // defer-max (T13)
        const float m_new = fmaxf(m_run, mt);
        const float al = exp2f(m_run - m_new);
        l_run *= al;
#pragma unroll
        for (int r = 0; r < 16; ++r) { ot0[r] *= al; ot1[r] *= al; }
        m_run = m_new;
      }
      // ---- exp2(fma) + sum ----
      float ls = 0.0f;
#pragma unroll
      for (int r = 0; r < 16; ++r) {
        st0[r] = exp2f(__builtin_fmaf(st0[r], SC, -m_run));
        st1[r] = exp2f(__builtin_fmaf(st1[r], SC, -m_run));
        ls += st0[r] + st1[r];
      }
      ls += __shfl_xor(ls, 32, 64);
      l_run += ls;
      // ---- P^T -> B-op (cvt_pk + permlane32_swap), PV ----
      __builtin_amdgcn_s_setprio(1);
#pragma unroll
      for (int ks = 0; ks < 4; ++ks) {
        const int ro = (ks & 1) * 8;
        unsigned w0, w1, w2, w3;
        if (ks < 2) {
          w0 = cvt_pk_bf16(st0[ro], st0[ro + 1]);
          w1 = cvt_pk_bf16(st0[ro + 2], st0[ro + 3]);
          w2 = cvt_pk_bf16(st0[ro + 4], st0[ro + 5]);
          w3 = cvt_pk_bf16(st0[ro + 6], st0[ro + 7]);
        } else {
          w0 = cvt_pk_bf16(st1[ro], st1[ro + 1]);
          w1 = cvt_pk_bf16(st1[ro + 2], st1[ro + 3]);
          w2 = cvt_pk_bf16(st1[ro + 4], st1[ro + 5]);
          w3 = cvt_pk_bf16(st1[ro + 6], st1[ro + 7]);
        }
        // after swap: w0=[w0lo|w2lo]=Breg0, w2=[w0hi|w2hi]=Breg2 (same for w1/w3)
        asm("v_permlane32_swap_b32 %0, %1" : "+v"(w0), "+v"(w2));
        asm("v_permlane32_swap_b32 %0, %1" : "+v"(w1), "+v"(w3));
        union { unsigned u[4]; short8 v; } pb;
        pb.u[0] = w0; pb.u[1] = w1; pb.u[2] = w2; pb.u[3] = w3;
        const int c = ((2 * ks + h32) ^ cxor) * 16;
        short8 v0 = *(const short8*)(Vbase + l31 * 128 + c);
        short8 v1 = *(const short8*)(Vbase + (32 + l31) * 128 + c);
        ot0 = mfma32(v0, pb.v, ot0);
        ot1 = mfma32(v1, pb.v, ot1);
      }
      __builtin_amdgcn_s_setprio(0);
    }
    __builtin_amdgcn_sched_barrier(0);
    asm volatile("" ::: "memory");
    __builtin_amdgcn_s_barrier();
    __builtin_amdgcn_sched_barrier(0);
  }
  // ---- epilogue: O^T -> Ao[q][h*64+d], lane-local 1/l ----
  const float inv = 1.0f / l_run;
  __hip_bfloat16* Op = Ao + (size_t)(b * SEQ + qg) * DM + h * 64;
#pragma unroll
  for (int r = 0; r < 16; r += 4) {
    const int d0 = 8 * (r >> 2) + 4 * h32;
    uint2 pk0, pk1;
    pk0.x = cvt_pk_bf16(ot0[r] * inv, ot0[r + 1] * inv);
    pk0.y = cvt_pk_bf16(ot0[r + 2] * inv, ot0[r + 3] * inv);
    *(uint2*)(Op + d0) = pk0;
    pk1.x = cvt_pk_bf16(ot1[r] * inv, ot1[r + 1] * inv);
    pk1.y = cvt_pk_bf16(ot1[r + 2] * inv, ot1[r + 3] * inv);
    *(uint2*)(Op + 32 + d0) = pk1;
  }
}

// ---------------- launch ----------------
extern "C" void kernel_launch(void* const* d_in, const int* in_sizes, int n_in,
                              void* d_out, int out_size, void* d_ws, size_t ws_size,
                              hipStream_t stream) {
  const float* x  = (const float*)d_in[0];
  const float* Wq = (const float*)d_in[1];
  const float* Wk = (const float*)d_in[2];
  const float* Wv = (const float*)d_in[3];
  const float* Wo = (const float*)d_in[4];
  char* ws = (char*)d_ws;
  __hip_bfloat16* xb   = (__hip_bfloat16*)ws;
  __hip_bfloat16* Ao   = (__hip_bfloat16*)ws;                  // aliases xb (dead by then)
  __hip_bfloat16* Wb   = (__hip_bfloat16*)(ws + 8388608);
  __hip_bfloat16* QKVb = (__hip_bfloat16*)(ws + 16777216);
  __hip_bfloat16* Vt   = (__hip_bfloat16*)(ws + 41943040);
  float2*         tab  = (float2*)(ws + 50331648);
  (void)hipFuncSetAttribute((const void*)gemm256,
                            hipFuncAttributeMaxDynamicSharedMemorySize, 131072);
  prep_kernel<<<4096, 256, 0, stream>>>(x, Wq, Wk, Wv, Wo, xb, Wb);
  rope_table_kernel<<<256, 256, 0, stream>>>(tab);
  gemm256<<<192, 512, 131072, stream>>>(xb, Wb, QKVb, 3072);
  rope_kernel<<<4096, 256, 0, stream>>>(QKVb, tab);
  transpose_v<<<dim3(32, 32), 256, 0, stream>>>(QKVb, Vt);
  attn_kernel<<<512, 256, 0, stream>>>(QKVb, Vt, Ao);
  gemm_bt<64><<<dim3(32, 16), 256, 0, stream>>>(Ao, Wb + 3 * 1048576, (float*)d_out, 1024);
}

// Round 8
// 190.523 us; speedup vs baseline: 1.0993x; 1.0993x over previous
//
#include <hip/hip_runtime.h>
#include <hip/hip_bf16.h>
#include <stdint.h>
#include <math.h>

#define SEQ 2048
#define DM 1024
#define NH 16
#define DK 64

typedef __attribute__((ext_vector_type(8))) short short8;
typedef __attribute__((ext_vector_type(4))) short short4v;
typedef __attribute__((ext_vector_type(4))) float f32x4;
typedef __attribute__((ext_vector_type(16))) float f32x16;

__device__ __forceinline__ float bf2f(unsigned short s) {
  unsigned u = ((unsigned)s) << 16; float f; __builtin_memcpy(&f, &u, 4); return f;
}
__device__ __forceinline__ unsigned short f2bf(float f) {
  unsigned u; __builtin_memcpy(&u, &f, 4);
  u += 0x7FFFu + ((u >> 16) & 1u);          // RNE
  return (unsigned short)(u >> 16);
}
__device__ __forceinline__ unsigned cvt_pk_bf16(float lo, float hi) {
  unsigned r;
  asm("v_cvt_pk_bf16_f32 %0, %1, %2" : "=v"(r) : "v"(lo), "v"(hi));
  return r;   // [bf16(hi)<<16 | bf16(lo)]
}
// cross-half (lane vs lane^32) reduce — R6-proven shfl path
__device__ __forceinline__ float xhalf_max(float x) {
  return fmaxf(x, __shfl_xor(x, 32, 64));
}
__device__ __forceinline__ float xhalf_sum(float x) {
  return x + __shfl_xor(x, 32, 64);
}
__device__ __forceinline__ f32x4 mfma16(short8 a, short8 b, f32x4 c) {
  return __builtin_amdgcn_mfma_f32_16x16x32_bf16(a, b, c, 0, 0, 0);
}
__device__ __forceinline__ f32x16 mfma32(short8 a, short8 b, f32x16 c) {
  return __builtin_amdgcn_mfma_f32_32x32x16_bf16(a, b, c, 0, 0, 0);
}
__device__ __forceinline__ void gload_lds16(const void* g, void* l) {
  __builtin_amdgcn_global_load_lds((const __attribute__((address_space(1))) void*)g,
                                   (__attribute__((address_space(3))) void*)l, 16, 0, 0);
}

// ---------------- prep: fp32 -> bf16 for x and the 4 weight matrices ----------------
__global__ __launch_bounds__(256) void prep_kernel(
    const float* __restrict__ x, const float* __restrict__ Wq,
    const float* __restrict__ Wk, const float* __restrict__ Wv,
    const float* __restrict__ Wo, __hip_bfloat16* __restrict__ xb,
    __hip_bfloat16* __restrict__ Wb) {
  int chunk = blockIdx.x * 256 + threadIdx.x;   // 1,048,576 chunks of 8 elems
  const float* src; __hip_bfloat16* dst;
  if (chunk < 524288) { src = x + (size_t)chunk * 8; dst = xb + (size_t)chunk * 8; }
  else {
    int wc = chunk - 524288; int wi = wc >> 17; int wo_ = wc & 131071;
    const float* Ws = (wi == 0) ? Wq : (wi == 1) ? Wk : (wi == 2) ? Wv : Wo;
    src = Ws + (size_t)wo_ * 8; dst = Wb + (size_t)wi * 1048576 + (size_t)wo_ * 8;
  }
  float4 a = *(const float4*)src; float4 b = *(const float4*)(src + 4);
  union { short8 v; unsigned short e[8]; } u;
  u.e[0] = f2bf(a.x); u.e[1] = f2bf(a.y); u.e[2] = f2bf(a.z); u.e[3] = f2bf(a.w);
  u.e[4] = f2bf(b.x); u.e[5] = f2bf(b.y); u.e[6] = f2bf(b.z); u.e[7] = f2bf(b.w);
  *(short8*)dst = u.v;
}

// ---------------- RoPE cos/sin table: [2048][32] float2 ----------------
__global__ __launch_bounds__(256) void rope_table_kernel(float2* __restrict__ tab) {
  int idx = blockIdx.x * 256 + threadIdx.x;   // 65536
  int s = idx >> 5, i = idx & 31;
  float fr = powf(10000.0f, -(float)i * (1.0f / 32.0f));
  float ang = (float)s * fr;
  tab[idx] = make_float2(cosf(ang), sinf(ang));
}

// ============ 256^2 8-phase GEMM (m201 template): C[M][N] = A @ W^T, bf16 ============
__global__ __launch_bounds__(512, 1) void gemm256(
    const __hip_bfloat16* __restrict__ A, const __hip_bfloat16* __restrict__ W,
    __hip_bfloat16* __restrict__ C, const int N) {
  extern __shared__ char lds[];
  char* ldsA = lds;              // 64KB: db(2) x half(2) x 16KB
  char* ldsB = lds + 65536;      // 64KB
  const int t = threadIdx.x;
  int wg = blockIdx.x;
  const int cpx = gridDim.x >> 3;                 // grid % 8 == 0
  wg = (wg & 7) * cpx + (wg >> 3);                // bijective XCD swizzle
  const int ntl = N >> 8;
  const int mt = wg / ntl, nt = wg % ntl;
  const int m0 = mt << 8, n0 = nt << 8;
  const int w = t >> 6, lane = t & 63, l15 = lane & 15, hi = lane >> 4;
  const int wm = w >> 2, wn = w & 3;
  const int lr = t >> 3;
  const int csw = ((t & 7) ^ (lr & 7)) * 8;       // inverse-swizzled source elem offset
  const __hip_bfloat16* aS = A + (size_t)(m0 + lr) * 1024 + csw;
  const __hip_bfloat16* bS = W + (size_t)(n0 + lr) * 1024 + csw;
  char* ldA1 = ldsA + t * 16; char* ldA2 = ldsA + (t + 512) * 16;
  char* ldB1 = ldsB + t * 16; char* ldB2 = ldsB + (t + 512) * 16;
#define STG_A(kt, db, mh) { \
    const __hip_bfloat16* s_ = aS + (size_t)(mh) * 131072 + (kt) * 64; \
    gload_lds16(s_,              ldA1 + (db) * 32768 + (mh) * 16384);  \
    gload_lds16(s_ + 65536,      ldA2 + (db) * 32768 + (mh) * 16384); }
#define STG_B(kt, db, nh) { \
    const __hip_bfloat16* s_ = bS + (size_t)(nh) * 131072 + (kt) * 64; \
    gload_lds16(s_,              ldB1 + (db) * 32768 + (nh) * 16384);  \
    gload_lds16(s_ + 65536,      ldB2 + (db) * 32768 + (nh) * 16384); }
  int lrA[4], lrB[2];
#pragma unroll
  for (int mi = 0; mi < 4; ++mi) lrA[mi] = wm * 64 + mi * 16 + l15;
#pragma unroll
  for (int ni = 0; ni < 2; ++ni) lrB[ni] = wn * 32 + ni * 16 + l15;
  f32x4 acc[8][4] = {};
  short8 afr[4][2], bfr[2][2][2];
  auto rdA = [&](int db, int mh) {
#pragma unroll
    for (int mi = 0; mi < 4; ++mi)
#pragma unroll
      for (int ks = 0; ks < 2; ++ks) {
        int off = db * 32768 + mh * 16384 + lrA[mi] * 128 +
                  ((((ks << 2) + hi) ^ (lrA[mi] & 7)) << 4);
        afr[mi][ks] = *(const short8*)(ldsA + off);
      }
  };
  auto rdB = [&](int db, int nh) {
#pragma unroll
    for (int ni = 0; ni < 2; ++ni)
#pragma unroll
      for (int ks = 0; ks < 2; ++ks) {
        int off = db * 32768 + nh * 16384 + lrB[ni] * 128 +
                  ((((ks << 2) + hi) ^ (lrB[ni] & 7)) << 4);
        bfr[nh][ni][ks] = *(const short8*)(ldsB + off);
      }
  };
  auto quad = [&](int mh, int nh) {
    __builtin_amdgcn_s_setprio(1);
#pragma unroll
    for (int mi = 0; mi < 4; ++mi)
#pragma unroll
      for (int ni = 0; ni < 2; ++ni)
#pragma unroll
        for (int ks = 0; ks < 2; ++ks)
          acc[mh * 4 + mi][nh * 2 + ni] =
              mfma16(afr[mi][ks], bfr[nh][ni][ks], acc[mh * 4 + mi][nh * 2 + ni]);
    __builtin_amdgcn_s_setprio(0);
  };
  // prologue: stage kt=0 (db=0), order [Alo, Blo, Bhi, Ahi]
  STG_A(0, 0, 0); STG_B(0, 0, 0); STG_B(0, 0, 1); STG_A(0, 0, 1);
  asm volatile("s_waitcnt vmcnt(4)" ::: "memory");   // Alo,Blo landed
  __builtin_amdgcn_s_barrier();
  for (int kt = 0; kt < 16; ++kt) {
    const int db = kt & 1, dn = db ^ 1;
    const bool nl = (kt < 15);
    // p0: quadrant (0,0)
    rdA(db, 0); rdB(db, 0);
    if (nl) { STG_A(kt + 1, dn, 0);
      asm volatile("s_waitcnt vmcnt(4)" ::: "memory"); }
    else     asm volatile("s_waitcnt vmcnt(2)" ::: "memory");
    __builtin_amdgcn_s_barrier();
    quad(0, 0);
    __builtin_amdgcn_s_barrier();
    // p1: quadrant (0,1)
    rdB(db, 1);
    if (nl) { STG_B(kt + 1, dn, 0);
      asm volatile("s_waitcnt vmcnt(4)" ::: "memory"); }
    else     asm volatile("s_waitcnt vmcnt(0)" ::: "memory");
    __builtin_amdgcn_s_barrier();
    quad(0, 1);
    __builtin_amdgcn_s_barrier();
    // p2: quadrant (1,0)
    rdA(db, 1);
    if (nl) { STG_B(kt + 1, dn, 1);
      asm volatile("s_waitcnt vmcnt(6)" ::: "memory"); }
    __builtin_amdgcn_s_barrier();
    quad(1, 0);
    __builtin_amdgcn_s_barrier();
    // p3: quadrant (1,1)
    if (nl) { STG_A(kt + 1, dn, 1);
      asm volatile("s_waitcnt vmcnt(4)" ::: "memory"); }
    __builtin_amdgcn_s_barrier();
    quad(1, 1);
    __builtin_amdgcn_s_barrier();
  }
#undef STG_A
#undef STG_B
  unsigned short* Cb = (unsigned short*)C;
#pragma unroll
  for (int MI = 0; MI < 8; ++MI) {
    const int m = m0 + (MI >> 2) * 128 + wm * 64 + (MI & 3) * 16 + hi * 4;
#pragma unroll
    for (int NI = 0; NI < 4; ++NI) {
      const int n = n0 + (NI >> 1) * 128 + wn * 32 + (NI & 1) * 16 + l15;
#pragma unroll
      for (int r = 0; r < 4; ++r)
        Cb[(size_t)(m + r) * N + n] = f2bf(acc[MI][NI][r]);
    }
  }
}

// ---------------- GEMM 128xBN (out-proj): C fp32 = A[M][1024] @ W[N][1024]^T ----
template<int BN>
__global__ __launch_bounds__(256) void gemm_bt(
    const __hip_bfloat16* __restrict__ A, const __hip_bfloat16* __restrict__ W,
    float* __restrict__ C, const int N) {
  constexpr int NI = BN / 32;
  constexpr int WN = BN / 2;
  __shared__ alignas(16) __hip_bfloat16 As[128 * 32];
  __shared__ alignas(16) __hip_bfloat16 Bs[BN * 32];
  const int t = threadIdx.x;
  const int m0 = blockIdx.x * 128, n0 = blockIdx.y * BN;
  const int w = t >> 6, lane = t & 63, l15 = lane & 15, hi = lane >> 4;
  const int wm = w >> 1, wn = w & 1;
  const int srow = t >> 2, scs = (t & 3) ^ (srow & 3);
  const __hip_bfloat16* aSrcA = A + (size_t)(m0 + srow) * DM + scs * 8;
  const __hip_bfloat16* aSrcB = aSrcA + (size_t)64 * DM;
  const __hip_bfloat16* bSrcA = W + (size_t)(n0 + srow) * DM + scs * 8;
  const __hip_bfloat16* bSrcB = bSrcA + (size_t)64 * DM;
  char* aDstA = (char*)As + t * 16; char* aDstB = (char*)As + (t + 256) * 16;
  char* bDstA = (char*)Bs + t * 16; char* bDstB = (char*)Bs + (t + 256) * 16;
  const int r3 = l15 & 3;
  int aoff[4], boff[NI];
#pragma unroll
  for (int i = 0; i < 4; ++i)
    aoff[i] = (wm * 64 + i * 16 + l15) * 64 + ((hi ^ r3) * 16);
#pragma unroll
  for (int i = 0; i < NI; ++i)
    boff[i] = (wn * WN + i * 16 + l15) * 64 + ((hi ^ r3) * 16);
  f32x4 acc[4][NI] = {};
  for (int kt = 0; kt < DM; kt += 32) {
    gload_lds16(aSrcA + kt, aDstA);
    gload_lds16(aSrcB + kt, aDstB);
    gload_lds16(bSrcA + kt, bDstA);
    if (BN == 128) gload_lds16(bSrcB + kt, bDstB);
    __syncthreads();
    short8 af[4], bfv[NI];
#pragma unroll
    for (int i = 0; i < 4; ++i) af[i] = *(const short8*)((const char*)As + aoff[i]);
#pragma unroll
    for (int i = 0; i < NI; ++i) bfv[i] = *(const short8*)((const char*)Bs + boff[i]);
#pragma unroll
    for (int mi = 0; mi < 4; ++mi)
#pragma unroll
      for (int ni = 0; ni < NI; ++ni)
        acc[mi][ni] = mfma16(af[mi], bfv[ni], acc[mi][ni]);
    __syncthreads();
  }
  const int mBase = m0 + wm * 64, nBase = n0 + wn * WN;
#pragma unroll
  for (int mi = 0; mi < 4; ++mi)
#pragma unroll
    for (int ni = 0; ni < NI; ++ni) {
      int m = mBase + mi * 16 + hi * 4, n = nBase + ni * 16 + l15;
#pragma unroll
      for (int r = 0; r < 4; ++r)
        C[(size_t)(m + r) * N + n] = acc[mi][ni][r];
    }
}

// ---------------- RoPE: rotate Q (cols 0..1023) and K (cols 1024..2047) in place ----
__global__ __launch_bounds__(256) void rope_kernel(
    __hip_bfloat16* __restrict__ QKV, const float2* __restrict__ tab) {
  int chunk = blockIdx.x * 256 + threadIdx.x;   // 4096 rows * 256 chunks
  int row = chunk >> 8; int c0 = (chunk & 255) << 3;
  int s = row & (SEQ - 1);
  const float2* tb = tab + s * 32 + ((c0 & 63) >> 1);
  __hip_bfloat16* p = QKV + (size_t)row * 3072 + c0;
  union { short8 v; unsigned short e[8]; } u; u.v = *(const short8*)p;
  union { short8 v; unsigned short e[8]; } o;
#pragma unroll
  for (int k = 0; k < 4; ++k) {
    float2 cs = tb[k];
    float x1 = bf2f(u.e[2 * k]), x2 = bf2f(u.e[2 * k + 1]);
    o.e[2 * k]     = f2bf(cs.x * x1 - cs.y * x2);
    o.e[2 * k + 1] = f2bf(cs.y * x1 + cs.x * x2);
  }
  *(short8*)p = o.v;
}

// ---------------- V transpose: Vt[bh][d][s] = V[b][s][h*64+d] ----------------
__global__ __launch_bounds__(256) void transpose_v(
    const __hip_bfloat16* __restrict__ QKV, __hip_bfloat16* __restrict__ Vt) {
  const int st = blockIdx.x, bh = blockIdx.y, b = bh >> 4, h = bh & 15;
  __shared__ alignas(16) __hip_bfloat16 tile[64][80];   // pad 16 -> 160B rows
  const int t = threadIdx.x, s0 = st * 64;
#pragma unroll
  for (int i = 0; i < 2; ++i) {
    int idx = i * 256 + t; int r = idx >> 3, c = idx & 7;
    short8 v = *(const short8*)(QKV + (size_t)(b * SEQ + s0 + r) * 3072 + 2048 + h * 64 + c * 8);
    *(short8*)&tile[r][c * 8] = v;
  }
  __syncthreads();
#pragma unroll
  for (int i = 0; i < 2; ++i) {
    int idx = i * 256 + t; int d = idx >> 3, c = idx & 7;
    union { short8 v; short e[8]; } u;
#pragma unroll
    for (int j = 0; j < 8; ++j) u.e[j] = *(short*)&tile[c * 8 + j][d];
    *(short8*)(Vt + ((size_t)bh * 64 + d) * SEQ + s0 + c * 8) = u.v;
  }
}

// ======== Flash attention R8: kv-split waves (2q x 2kv), 32x32 MFMA, lane-local SM ====
// Same as R7 except: (a) cross-half reduce via __shfl_xor (R6-proven) instead of
// permlane asm; (b) NaN-proof combine (a1/a2 gated on l>0, inv gated on denom>0).
__global__ __launch_bounds__(256) void attn_kernel(
    const __hip_bfloat16* __restrict__ QKV, const __hip_bfloat16* __restrict__ Vt,
    __hip_bfloat16* __restrict__ Ao) {
  const int id = blockIdx.x;
  const int bh = (id & 7) * 4 + ((id >> 3) & 3);   // id%8 constant per bh -> same XCD
  const int qb = 31 - (id >> 5);                   // 0..31, heavy-first
  const int b = bh >> 4, h = bh & 15;
  __shared__ alignas(16) __hip_bfloat16 Ks[2][64 * 64];
  __shared__ alignas(16) __hip_bfloat16 Vs[2][64 * 64];
  const int t = threadIdx.x, w = t >> 6, lane = t & 63;
  const int l31 = lane & 31, h32 = lane >> 5;
  const int wq = w & 1, wk = w >> 1;
  const int qg = qb * 64 + wq * 32 + l31;          // this lane's q row
  const int ib = 2 * qb + wq;                      // q 32-block index
  const int nt = qb + 1;                           // KV tiles (64 each)
  constexpr float SC = 0.18033688f;                // 0.125 * log2(e)
  constexpr float THR = 11.541560f;                // 8 nats in log2
  // Q fragments (B-operand): lane col q=l31, k = kk*16 + h32*8 + j
  const __hip_bfloat16* Qp = QKV + (size_t)(b * SEQ + qg) * 3072 + h * 64 + h32 * 8;
  short8 qf[4];
#pragma unroll
  for (int kk = 0; kk < 4; ++kk) qf[kk] = *(const short8*)(Qp + kk * 16);
  // staging: 256 threads x (2 K + 2 V) 16B chunks per 64-row tile
  const int sr = t >> 3, sc = t & 7, scs = sc ^ (sr & 7);
  const __hip_bfloat16* kSrcA = QKV + (size_t)(b * SEQ + sr) * 3072 + DM + h * 64 + scs * 8;
  const __hip_bfloat16* kSrcB = kSrcA + (size_t)32 * 3072;
  const __hip_bfloat16* vSrcA = Vt + ((size_t)bh * 64 + sr) * SEQ + scs * 8;
  const __hip_bfloat16* vSrcB = vSrcA + (size_t)32 * SEQ;
  char* kDstA = (char*)Ks + t * 16;  char* kDstB = (char*)Ks + (t + 256) * 16;
  char* vDstA = (char*)Vs + t * 16;  char* vDstB = (char*)Vs + (t + 256) * 16;
  f32x16 ot0 = {}, ot1 = {};                       // O^T acc: d 0..31 / 32..63
  float m_run = -INFINITY, l_run = 0.0f;

  // stage tile 0 -> buf 0
  gload_lds16(kSrcA, kDstA);
  gload_lds16(kSrcB, kDstB);
  gload_lds16(vSrcA, vDstA);
  gload_lds16(vSrcB, vDstB);

  for (int kvt = 0; kvt < nt; ++kvt) {
    const int cur = kvt & 1;
    if (kvt + 1 < nt) {
      const size_t ko = (size_t)((kvt + 1) * 64) * 3072;
      const int vo = (kvt + 1) * 64;
      gload_lds16(kSrcA + ko, kDstA + (cur ^ 1) * 8192);
      gload_lds16(kSrcB + ko, kDstB + (cur ^ 1) * 8192);
      gload_lds16(vSrcA + vo, vDstA + (cur ^ 1) * 8192);
      gload_lds16(vSrcB + vo, vDstB + (cur ^ 1) * 8192);
      __builtin_amdgcn_sched_barrier(0);
      asm volatile("s_waitcnt vmcnt(4)" ::: "memory");
    } else {
      __builtin_amdgcn_sched_barrier(0);
      asm volatile("s_waitcnt vmcnt(0)" ::: "memory");
    }
    __builtin_amdgcn_s_barrier();
    __builtin_amdgcn_sched_barrier(0);

    const int ia = 2 * kvt + wk;                   // kv 32-block index
    if (ia <= ib) {                                // wave-uniform causal skip
      const char* Kbase = (const char*)Ks + cur * 8192;
      const char* Vbase = (const char*)Vs + cur * 8192;
      const int cxor = l31 & 7;
      const int krow = (wk * 32 + l31) * 128;
      // ---- QK^T quadrant: S^T[kv 32][q 32] ----
      f32x16 st = {};
      __builtin_amdgcn_s_setprio(1);
#pragma unroll
      for (int kk = 0; kk < 4; ++kk) {
        short8 k0 = *(const short8*)(Kbase + krow + (((2 * kk + h32) ^ cxor) * 16));
        st = mfma32(k0, qf[kk], st);
      }
      __builtin_amdgcn_s_setprio(0);
      // ---- diag mask (ia == ib): kv co <= l31 ----
      if (ia == ib) {
#pragma unroll
        for (int r = 0; r < 16; ++r) {
          const int co = (r & 3) + 8 * (r >> 2) + 4 * h32;
          st[r] = (co <= l31) ? st[r] : -INFINITY;
        }
      }
      // ---- per-row max: tree + cross-half shfl ----
      float tm[8];
#pragma unroll
      for (int r = 0; r < 8; ++r) tm[r] = fmaxf(st[r], st[r + 8]);
#pragma unroll
      for (int s = 4; s > 0; s >>= 1)
#pragma unroll
        for (int r = 0; r < s; ++r) tm[r] = fmaxf(tm[r], tm[r + s]);
      const float mt = xhalf_max(tm[0]) * SC;
      if (!__all(mt <= m_run + THR)) {             // defer-max (T13)
        const float m_new = fmaxf(m_run, mt);
        const float al = exp2f(m_run - m_new);
        l_run *= al;
#pragma unroll
        for (int r = 0; r < 16; ++r) { ot0[r] *= al; ot1[r] *= al; }
        m_run = m_new;
      }
      // ---- exp2 + sum ----
      float ls = 0.0f;
#pragma unroll
      for (int r = 0; r < 16; ++r) {
        st[r] = exp2f(__builtin_fmaf(st[r], SC, -m_run));
        ls += st[r];
      }
      l_run += xhalf_sum(ls);
      // ---- P^T -> B-op (cvt_pk + permlane32_swap), PV ----
      __builtin_amdgcn_s_setprio(1);
#pragma unroll
      for (int ks = 0; ks < 2; ++ks) {
        const int ro = ks * 8;
        unsigned w0 = cvt_pk_bf16(st[ro], st[ro + 1]);
        unsigned w1 = cvt_pk_bf16(st[ro + 2], st[ro + 3]);
        unsigned w2 = cvt_pk_bf16(st[ro + 4], st[ro + 5]);
        unsigned w3 = cvt_pk_bf16(st[ro + 6], st[ro + 7]);
        asm("v_permlane32_swap_b32 %0, %1" : "+v"(w0), "+v"(w2));
        asm("v_permlane32_swap_b32 %0, %1" : "+v"(w1), "+v"(w3));
        union { unsigned u[4]; short8 v; } pb;
        pb.u[0] = w0; pb.u[1] = w1; pb.u[2] = w2; pb.u[3] = w3;
        const int cch = ((wk * 4 + ks * 2 + h32) ^ cxor) * 16;
        short8 v0 = *(const short8*)(Vbase + l31 * 128 + cch);
        short8 v1 = *(const short8*)(Vbase + (32 + l31) * 128 + cch);
        ot0 = mfma32(v0, pb.v, ot0);               // d 0..31
        ot1 = mfma32(v1, pb.v, ot1);               // d 32..63
      }
      __builtin_amdgcn_s_setprio(0);
    }
    __builtin_amdgcn_sched_barrier(0);
    asm volatile("" ::: "memory");
    __builtin_amdgcn_s_barrier();
    __builtin_amdgcn_sched_barrier(0);
  }

  // ---- cross-wave flash combine: wk=1 -> LDS (dead K buffer), wk=0 merges ----
  if (wk == 1) {
    char* dst = (char*)Ks + wq * 8192 + lane * 128;
    const int sw = lane & 7;
#pragma unroll
    for (int c = 0; c < 4; ++c) {
      f32x4 v0 = { ot0[4 * c], ot0[4 * c + 1], ot0[4 * c + 2], ot0[4 * c + 3] };
      f32x4 v1 = { ot1[4 * c], ot1[4 * c + 1], ot1[4 * c + 2], ot1[4 * c + 3] };
      *(f32x4*)(dst + ((c ^ sw) * 16)) = v0;
      *(f32x4*)(dst + (((c + 4) ^ sw) * 16)) = v1;
    }
    *(float2*)((char*)Vs + wq * 512 + lane * 8) = make_float2(m_run, l_run);
  }
  __syncthreads();
  if (wk == 0) {
    const char* src = (const char*)Ks + wq * 8192 + lane * 128;
    const int sw = lane & 7;
    const float2 ml = *(const float2*)((const char*)Vs + wq * 512 + lane * 8);
    const float m2 = ml.x, l2 = ml.y;
    // NaN-proof merge: empty partitions (l==0) contribute exactly 0; no
    // exp2f of (-inf - -inf) is ever evaluated.
    const float mN = fmaxf(m_run, m2);
    const float a1 = (l_run > 0.0f) ? exp2f(m_run - mN) : 0.0f;
    const float a2 = (l2 > 0.0f) ? exp2f(m2 - mN) : 0.0f;
    const float denom = l_run * a1 + l2 * a2;
    const float inv = (denom > 0.0f) ? 1.0f / denom : 0.0f;
    __hip_bfloat16* Op = Ao + (size_t)(b * SEQ + qg) * DM + h * 64;
#pragma unroll
    for (int c = 0; c < 4; ++c) {
      const f32x4 p0 = *(const f32x4*)(src + ((c ^ sw) * 16));
      const f32x4 p1 = *(const f32x4*)(src + (((c + 4) ^ sw) * 16));
      const int r = 4 * c;
      const int d0 = 8 * c + 4 * h32;              // co(r..r+3) = d0..d0+3
      uint2 pk0, pk1;
      pk0.x = cvt_pk_bf16((ot0[r] * a1 + p0[0] * a2) * inv,
                          (ot0[r + 1] * a1 + p0[1] * a2) * inv);
      pk0.y = cvt_pk_bf16((ot0[r + 2] * a1 + p0[2] * a2) * inv,
                          (ot0[r + 3] * a1 + p0[3] * a2) * inv);
      *(uint2*)(Op + d0) = pk0;
      pk1.x = cvt_pk_bf16((ot1[r] * a1 + p1[0] * a2) * inv,
                          (ot1[r + 1] * a1 + p1[1] * a2) * inv);
      pk1.y = cvt_pk_bf16((ot1[r + 2] * a1 + p1[2] * a2) * inv,
                          (ot1[r + 3] * a1 + p1[3] * a2) * inv);
      *(uint2*)(Op + 32 + d0) = pk1;
    }
  }
}

// ---------------- launch ----------------
extern "C" void kernel_launch(void* const* d_in, const int* in_sizes, int n_in,
                              void* d_out, int out_size, void* d_ws, size_t ws_size,
                              hipStream_t stream) {
  const float* x  = (const float*)d_in[0];
  const float* Wq = (const float*)d_in[1];
  const float* Wk = (const float*)d_in[2];
  const float* Wv = (const float*)d_in[3];
  const float* Wo = (const float*)d_in[4];
  char* ws = (char*)d_ws;
  __hip_bfloat16* xb   = (__hip_bfloat16*)ws;
  __hip_bfloat16* Ao   = (__hip_bfloat16*)ws;                  // aliases xb (dead by then)
  __hip_bfloat16* Wb   = (__hip_bfloat16*)(ws + 8388608);
  __hip_bfloat16* QKVb = (__hip_bfloat16*)(ws + 16777216);
  __hip_bfloat16* Vt   = (__hip_bfloat16*)(ws + 41943040);
  float2*         tab  = (float2*)(ws + 50331648);
  (void)hipFuncSetAttribute((const void*)gemm256,
                            hipFuncAttributeMaxDynamicSharedMemorySize, 131072);
  prep_kernel<<<4096, 256, 0, stream>>>(x, Wq, Wk, Wv, Wo, xb, Wb);
  rope_table_kernel<<<256, 256, 0, stream>>>(tab);
  gemm256<<<192, 512, 131072, stream>>>(xb, Wb, QKVb, 3072);
  rope_kernel<<<4096, 256, 0, stream>>>(QKVb, tab);
  transpose_v<<<dim3(32, 32), 256, 0, stream>>>(QKVb, Vt);
  attn_kernel<<<1024, 256, 0, stream>>>(QKVb, Vt, Ao);
  gemm_bt<64><<<dim3(32, 16), 256, 0, stream>>>(Ao, Wb + 3 * 1048576, (float*)d_out, 1024);
}